// Round 2
// baseline (685.319 us; speedup 1.0000x reference)
//
#include <hip/hip_runtime.h>
#include <math.h>

// Problem constants (match reference)
constexpr int BATCH  = 65536;
constexpr int INFEAT = 2048;
constexpr int GROUP  = 256;          // rows per max-group
constexpr int TPB    = 1024;         // 16 waves per block
constexpr int WAVES  = TPB / 64;     // 16
constexpr int ROWS_PER_WAVE = GROUP / WAVES; // 16

// One block per 256-row group; one wave per row-pair per iteration.
// 2-row interleave: 16 float4 loads in flight, 4 independent FMA chains,
// 2 interleaved shuffle-reduce chains -> loads stay outstanding during the
// reduce/tanh tail instead of convoying on vmcnt(0).
__global__ __launch_bounds__(TPB) void fused_gemv_gelu_max(
    const float* __restrict__ x,
    const float* __restrict__ w,
    const float* __restrict__ bias,
    float* __restrict__ out)
{
    const int grp      = blockIdx.x;          // 0..255
    const int row_base = grp * GROUP;
    const int wave     = threadIdx.x >> 6;    // 0..15
    const int lane     = threadIdx.x & 63;

    // Zero this group's 256 output slots (harness poisons d_out with 0xAA).
    if (threadIdx.x < GROUP) out[row_base + threadIdx.x] = 0.0f;

    // Weight fragment: lane holds 32 floats of w in 32 VGPRs, loaded once.
    float4 wr[8];
    const float4* w4 = reinterpret_cast<const float4*>(w);
    #pragma unroll
    for (int j = 0; j < 8; ++j) wr[j] = w4[j * 64 + lane];

    const float b4 = bias[0] * 0.25f;   // fused (acc + b) * 0.25
    float wmax = -INFINITY;

    const int row0 = row_base + wave * ROWS_PER_WAVE;
    const float4* xbase =
        reinterpret_cast<const float4*>(x) + (size_t)row0 * (INFEAT / 4) + lane;

    for (int r = 0; r < ROWS_PER_WAVE; r += 2) {
        const float4* p0 = xbase + (size_t)r * (INFEAT / 4);
        const float4* p1 = p0 + (INFEAT / 4);

        float4 a[8], c[8];
        #pragma unroll
        for (int j = 0; j < 8; ++j) a[j] = p0[j * 64];   // row r   : 8 KiB
        #pragma unroll
        for (int j = 0; j < 8; ++j) c[j] = p1[j * 64];   // row r+1 : 8 KiB

        // 4 independent FMA chains (2 per row) to break dep-latency.
        float s0a = 0.f, s0b = 0.f, s1a = 0.f, s1b = 0.f;
        #pragma unroll
        for (int j = 0; j < 8; j += 2) {
            s0a = fmaf(a[j].x, wr[j].x, s0a);
            s0a = fmaf(a[j].y, wr[j].y, s0a);
            s0a = fmaf(a[j].z, wr[j].z, s0a);
            s0a = fmaf(a[j].w, wr[j].w, s0a);
            s0b = fmaf(a[j+1].x, wr[j+1].x, s0b);
            s0b = fmaf(a[j+1].y, wr[j+1].y, s0b);
            s0b = fmaf(a[j+1].z, wr[j+1].z, s0b);
            s0b = fmaf(a[j+1].w, wr[j+1].w, s0b);
            s1a = fmaf(c[j].x, wr[j].x, s1a);
            s1a = fmaf(c[j].y, wr[j].y, s1a);
            s1a = fmaf(c[j].z, wr[j].z, s1a);
            s1a = fmaf(c[j].w, wr[j].w, s1a);
            s1b = fmaf(c[j+1].x, wr[j+1].x, s1b);
            s1b = fmaf(c[j+1].y, wr[j+1].y, s1b);
            s1b = fmaf(c[j+1].z, wr[j+1].z, s1b);
            s1b = fmaf(c[j+1].w, wr[j+1].w, s1b);
        }
        float acc0 = s0a + s0b;
        float acc1 = s1a + s1b;

        // Two interleaved 64-lane butterfly sums (independent ds chains).
        #pragma unroll
        for (int off = 32; off >= 1; off >>= 1) {
            float t0 = __shfl_xor(acc0, off, 64);
            float t1 = __shfl_xor(acc1, off, 64);
            acc0 += t0;
            acc1 += t1;
        }

        // p = (dot + bias)/4 ; s = 2*gelu_tanh(p) = p*(1+tanh(...))
        float pA = fmaf(acc0, 0.25f, b4);
        float pB = fmaf(acc1, 0.25f, b4);
        float tA = tanhf(0.7978845608f * fmaf(0.044715f * pA * pA, pA, pA));
        float tB = tanhf(0.7978845608f * fmaf(0.044715f * pB * pB, pB, pB));
        wmax = fmaxf(wmax, pA * (1.0f + tA));
        wmax = fmaxf(wmax, pB * (1.0f + tB));
    }

    // Cross-wave max via LDS; thread 0 writes the single group result.
    __shared__ float smax[WAVES];
    if (lane == 0) smax[wave] = wmax;
    __syncthreads();
    if (threadIdx.x == 0) {
        float m = smax[0];
        #pragma unroll
        for (int i = 1; i < WAVES; ++i) m = fmaxf(m, smax[i]);
        out[row_base] = m;   // ordered after the zeroing by __syncthreads
    }
}

extern "C" void kernel_launch(void* const* d_in, const int* in_sizes, int n_in,
                              void* d_out, int out_size, void* d_ws, size_t ws_size,
                              hipStream_t stream) {
    const float* x   = (const float*)d_in[0];
    const float* w   = (const float*)d_in[1];
    const float* b   = (const float*)d_in[2];
    float*       out = (float*)d_out;

    dim3 grid(BATCH / GROUP);   // 256 blocks, 1 per CU
    dim3 block(TPB);            // 1024 threads = 16 waves
    hipLaunchKernelGGL(fused_gemv_gelu_max, grid, block, 0, stream,
                       x, w, b, out);
}